// Round 10
// baseline (241.013 us; speedup 1.0000x reference)
//
#include <hip/hip_runtime.h>

#define BB 8
#define NN 2048
#define FF 128

// ws float layout:
//   [0, 131072)        xpart (1024 blocks x 128 col-sums of X)
//   [131072, 132096)   S (BB*FF)
//   [132096, 148480)   p (BB*NN)
//   [148480, 164864)   r (BB*NN)
//   [164864, ...)      pk: u32[B*N*64] in-lane masks (4 MB)
//                      bit (it*4+j) of pk[row*64+lane] = (A[row][it*256+lane*4+j] != 0)

// kA: (1) p[row] = exp(X[row,:].w_ai), xpart col-sums  (2) bit-pack A -> pk.
// grid 1024 x 256; 16 rows/block; pack: 4 rows/wave in two 16-load batches.
__global__ __launch_bounds__(256) void kA_pack_p(const float* __restrict__ X,
                                                 const float* __restrict__ A,
                                                 const float* __restrict__ W,
                                                 const float* __restrict__ av,
                                                 float* __restrict__ p,
                                                 float* __restrict__ xpart,
                                                 unsigned* __restrict__ pk) {
    __shared__ float wls[FF];
    __shared__ float xls[FF];
    const int t = threadIdx.x;
    if (t < FF) {
        const float4* W4 = (const float4*)(W + t * FF);
        const float4* a4 = (const float4*)(av + FF);
        float s = 0.f;
#pragma unroll
        for (int f = 0; f < FF / 4; ++f) {
            const float4 w4 = W4[f], aa = a4[f];
            s += w4.x * aa.x + w4.y * aa.y + w4.z * aa.z + w4.w * aa.w;
        }
        wls[t] = s;
        xls[t] = 0.f;
    }
    __syncthreads();

    const int blk = blockIdx.x;
    const int row0 = blk * 16;
    const int lane = t & 63, wave = t >> 6;
    const int half = lane >> 5, l32 = lane & 31;

    // ---- p + column sums for the block's 16 rows (half-wave per row) ----
    {
        const float4 wv = ((const float4*)wls)[l32];
        float4 cs = make_float4(0.f, 0.f, 0.f, 0.f);
        const float4* X4 = (const float4*)(X + (size_t)row0 * FF);
#pragma unroll
        for (int k = 0; k < 2; ++k) {
            const int rloc = wave * 4 + k * 2 + half;
            const float4 xv = X4[rloc * 32 + l32];
            cs.x += xv.x; cs.y += xv.y; cs.z += xv.z; cs.w += xv.w;
            float s = xv.x * wv.x + xv.y * wv.y + xv.z * wv.z + xv.w * wv.w;
#pragma unroll
            for (int off = 16; off; off >>= 1) s += __shfl_xor(s, off, 64);
            if (l32 == 0) p[row0 + rloc] = expf(s);
        }
        atomicAdd(&xls[l32 * 4 + 0], cs.x);
        atomicAdd(&xls[l32 * 4 + 1], cs.y);
        atomicAdd(&xls[l32 * 4 + 2], cs.z);
        atomicAdd(&xls[l32 * 4 + 3], cs.w);
    }
    __syncthreads();
    if (t < FF) xpart[blk * FF + t] = xls[t];

    // ---- pure A streaming: 4 rows/wave, two 2-row 16-load batches ----
    const int rbase = row0 + wave * 4;
#pragma unroll 1
    for (int g = 0; g < 2; ++g) {
        const int rowA = rbase + g * 2;
        const int rowB = rowA + 1;
        const float4* Aa = (const float4*)(A + (size_t)rowA * NN);
        const float4* Ab = (const float4*)(A + (size_t)rowB * NN);
        const float4 va0 = Aa[0 * 64 + lane], va1 = Aa[1 * 64 + lane];
        const float4 va2 = Aa[2 * 64 + lane], va3 = Aa[3 * 64 + lane];
        const float4 va4 = Aa[4 * 64 + lane], va5 = Aa[5 * 64 + lane];
        const float4 va6 = Aa[6 * 64 + lane], va7 = Aa[7 * 64 + lane];
        const float4 vb0 = Ab[0 * 64 + lane], vb1 = Ab[1 * 64 + lane];
        const float4 vb2 = Ab[2 * 64 + lane], vb3 = Ab[3 * 64 + lane];
        const float4 vb4 = Ab[4 * 64 + lane], vb5 = Ab[5 * 64 + lane];
        const float4 vb6 = Ab[6 * 64 + lane], vb7 = Ab[7 * 64 + lane];
        __builtin_amdgcn_sched_barrier(0);
        unsigned mA = 0u, mB = 0u;
#define NIB(v) ((v.x != 0.f ? 1u : 0u) | (v.y != 0.f ? 2u : 0u) | \
                (v.z != 0.f ? 4u : 0u) | (v.w != 0.f ? 8u : 0u))
        mA |= NIB(va0) << 0;  mA |= NIB(va1) << 4;  mA |= NIB(va2) << 8;  mA |= NIB(va3) << 12;
        mA |= NIB(va4) << 16; mA |= NIB(va5) << 20; mA |= NIB(va6) << 24; mA |= NIB(va7) << 28;
        mB |= NIB(vb0) << 0;  mB |= NIB(vb1) << 4;  mB |= NIB(vb2) << 8;  mB |= NIB(vb3) << 12;
        mB |= NIB(vb4) << 16; mB |= NIB(vb5) << 20; mB |= NIB(vb6) << 24; mB |= NIB(vb7) << 28;
#undef NIB
        pk[(size_t)rowA * 64 + lane] = mA;
        pk[(size_t)rowB * 64 + lane] = mB;
    }
}

// kB: block 0: xsum = reduce(xpart, 128 partials); S = xsum . W.
//     blocks 1..2048: r[row] = p[row] / (pk[row,:] . p[b,:]) (0 if denom==0)
__global__ __launch_bounds__(256) void kB_r(const float* __restrict__ W,
                                            const float* __restrict__ xpart,
                                            const float* __restrict__ p,
                                            const unsigned* __restrict__ pk,
                                            float* __restrict__ r,
                                            float* __restrict__ S) {
    __shared__ float p_lds[NN];
    const int t = threadIdx.x;

    if (blockIdx.x == 0) {
#pragma unroll
        for (int k = 0; k < 4; ++k) {
            const int o = t + 256 * k;            // (b,f), o in [0,1024)
            const int b = o >> 7, f = o & 127;
            float s = 0.f;
            for (int j = 0; j < 128; ++j) s += xpart[(b * 128 + j) * FF + f];
            p_lds[o] = s;
        }
        __syncthreads();
#pragma unroll
        for (int k = 0; k < 4; ++k) {
            const int o = t + 256 * k;
            const int b = o >> 7, f = o & 127;
            float s = 0.f;
#pragma unroll 8
            for (int c = 0; c < FF; ++c) s += p_lds[b * FF + c] * W[c * FF + f];
            S[o] = s;
        }
        return;
    }

    const int row0 = (blockIdx.x - 1) * 8;
    const int b = row0 >> 11;
    const float4* p4 = (const float4*)(p + (size_t)b * NN);
    float4* pl4 = (float4*)p_lds;
    pl4[t]       = p4[t];
    pl4[t + 256] = p4[t + 256];
    __syncthreads();

    const int lane = t & 63, wave = t >> 6;
    const int rowA = row0 + wave * 2;
    const int rowB = rowA + 1;
    const unsigned wA = pk[(size_t)rowA * 64 + lane];
    const unsigned wB = pk[(size_t)rowB * 64 + lane];

    float accA = 0.f, accB = 0.f;
#pragma unroll
    for (int it = 0; it < 8; ++it) {
        const float4 pv = pl4[it * 64 + lane];
        const unsigned na = (wA >> (it * 4)) & 15u;
        const unsigned nb = (wB >> (it * 4)) & 15u;
        accA += (na & 1u) ? pv.x : 0.f;  accB += (nb & 1u) ? pv.x : 0.f;
        accA += (na & 2u) ? pv.y : 0.f;  accB += (nb & 2u) ? pv.y : 0.f;
        accA += (na & 4u) ? pv.z : 0.f;  accB += (nb & 4u) ? pv.z : 0.f;
        accA += (na & 8u) ? pv.w : 0.f;  accB += (nb & 8u) ? pv.w : 0.f;
    }
#pragma unroll
    for (int off = 32; off; off >>= 1) {
        accA += __shfl_xor(accA, off, 64);
        accB += __shfl_xor(accB, off, 64);
    }
    if (lane == 0) {
        const int lr = rowA & (NN - 1);
        r[rowA] = (accA != 0.f) ? (p_lds[lr] / accA) : 0.f;
        r[rowB] = (accB != 0.f) ? (p_lds[lr + 1] / accB) : 0.f;
    }
}

// kC: H[row,f] = (pk[row,:] . r[b,:]) * S[b,f] + bias_W[f]
__global__ __launch_bounds__(256) void kC_H(const unsigned* __restrict__ pk,
                                            const float* __restrict__ rr,
                                            const float* __restrict__ S,
                                            const float* __restrict__ bias_W,
                                            float* __restrict__ Hout) {
    __shared__ float r_lds[NN];
    __shared__ float sls[FF], bwls[FF];
    const int t = threadIdx.x;
    const int row0 = blockIdx.x * 8;
    const int b = row0 >> 11;

    const float4* r4 = (const float4*)(rr + (size_t)b * NN);
    float4* rl4 = (float4*)r_lds;
    rl4[t]       = r4[t];
    rl4[t + 256] = r4[t + 256];
    if (t < FF) { sls[t] = S[b * FF + t]; bwls[t] = bias_W[t]; }
    __syncthreads();

    const int lane = t & 63, wave = t >> 6;
    const int rowA = row0 + wave * 2;
    const int rowB = rowA + 1;
    const unsigned wA = pk[(size_t)rowA * 64 + lane];
    const unsigned wB = pk[(size_t)rowB * 64 + lane];

    float accA = 0.f, accB = 0.f;
#pragma unroll
    for (int it = 0; it < 8; ++it) {
        const float4 rv = rl4[it * 64 + lane];
        const unsigned na = (wA >> (it * 4)) & 15u;
        const unsigned nb = (wB >> (it * 4)) & 15u;
        accA += (na & 1u) ? rv.x : 0.f;  accB += (nb & 1u) ? rv.x : 0.f;
        accA += (na & 2u) ? rv.y : 0.f;  accB += (nb & 2u) ? rv.y : 0.f;
        accA += (na & 4u) ? rv.z : 0.f;  accB += (nb & 4u) ? rv.z : 0.f;
        accA += (na & 8u) ? rv.w : 0.f;  accB += (nb & 8u) ? rv.w : 0.f;
    }
#pragma unroll
    for (int off = 32; off; off >>= 1) {
        accA += __shfl_xor(accA, off, 64);
        accB += __shfl_xor(accB, off, 64);
    }

    const float2 sv = ((const float2*)sls)[lane];
    const float2 bv = ((const float2*)bwls)[lane];
    float2* H2 = (float2*)Hout;
    H2[(size_t)rowA * 64 + lane] = make_float2(accA * sv.x + bv.x, accA * sv.y + bv.y);
    H2[(size_t)rowB * 64 + lane] = make_float2(accB * sv.x + bv.x, accB * sv.y + bv.y);
}

extern "C" void kernel_launch(void* const* d_in, const int* in_sizes, int n_in,
                              void* d_out, int out_size, void* d_ws, size_t ws_size,
                              hipStream_t stream) {
    const float* X      = (const float*)d_in[0];
    const float* A      = (const float*)d_in[1];
    const float* W      = (const float*)d_in[2];
    const float* a      = (const float*)d_in[3];
    // d_in[4] = bias_a : algebraically cancels (rank-1 den), unused
    const float* bias_W = (const float*)d_in[5];
    float* out = (float*)d_out;

    float* ws    = (float*)d_ws;
    float* xpart = ws;             // 1024*128 = 131072
    float* S     = ws + 131072;    // 1024
    float* p     = ws + 132096;    // 16384
    float* r     = ws + 148480;    // 16384
    unsigned* pk = (unsigned*)(ws + 164864);  // u32[B*N*64] = 4 MB

    kA_pack_p<<<(BB * NN) / 16, 256, 0, stream>>>(X, A, W, a, p, xpart, pk);
    kB_r<<<(BB * NN) / 8 + 1, 256, 0, stream>>>(W, xpart, p, pk, r, S);
    kC_H<<<(BB * NN) / 8, 256, 0, stream>>>(pk, r, S, bias_W, out);
}

// Round 11
// 236.948 us; speedup vs baseline: 1.0172x; 1.0172x over previous
//
#include <hip/hip_runtime.h>

#define BB 8
#define NN 2048
#define FF 128

// ws float layout:
//   [0, 65536)      xpart (512 blocks x 128 col-sums of X)
//   [65536, 66560)  S (BB*FF)
//   [66560, 82944)  p (BB*NN)
//   [82944, 99328)  r (BB*NN)
//   [99328, ...)    pk: u32[B*N*64] in-lane masks (4 MB)
//                   bit (it*4+j) of pk[row*64+lane] = (A[row][it*256+lane*4+j] != 0)

// kX: p[b,n] = exp(X[b,n,:] . w_ai); xpart[blk,:] = column sums of X slice.
// grid 512 x 256; 32 rows/block; half-wave per row. (R9 k1, proven)
__global__ __launch_bounds__(256) void kX_p_xsum(const float* __restrict__ X,
                                                 const float* __restrict__ W,
                                                 const float* __restrict__ av,
                                                 float* __restrict__ p,
                                                 float* __restrict__ xpart) {
    __shared__ float wls[FF];
    __shared__ float xls[FF];
    const int t = threadIdx.x;
    if (t < FF) {
        const float4* W4 = (const float4*)(W + t * FF);
        const float4* a4 = (const float4*)(av + FF);
        float s = 0.f;
#pragma unroll
        for (int f = 0; f < FF / 4; ++f) {
            const float4 w4 = W4[f], aa = a4[f];
            s += w4.x * aa.x + w4.y * aa.y + w4.z * aa.z + w4.w * aa.w;
        }
        wls[t] = s;
        xls[t] = 0.f;
    }
    __syncthreads();

    const int gr0 = blockIdx.x * 32;
    const int lane = t & 63, wave = t >> 6;
    const int half = lane >> 5, l32 = lane & 31;
    const float4 wv = ((const float4*)wls)[l32];
    float4 cs = make_float4(0.f, 0.f, 0.f, 0.f);
    const float4* X4 = (const float4*)(X + (size_t)gr0 * FF);

#pragma unroll
    for (int it = 0; it < 4; ++it) {
        const int rloc = wave * 8 + it * 2 + half;
        const float4 xv = X4[(size_t)rloc * 32 + l32];
        cs.x += xv.x; cs.y += xv.y; cs.z += xv.z; cs.w += xv.w;
        float s = xv.x * wv.x + xv.y * wv.y + xv.z * wv.z + xv.w * wv.w;
#pragma unroll
        for (int off = 16; off; off >>= 1) s += __shfl_xor(s, off, 64);
        if (l32 == 0) p[gr0 + rloc] = expf(s);
    }

    atomicAdd(&xls[l32 * 4 + 0], cs.x);
    atomicAdd(&xls[l32 * 4 + 1], cs.y);
    atomicAdd(&xls[l32 * 4 + 2], cs.z);
    atomicAdd(&xls[l32 * 4 + 3], cs.w);
    __syncthreads();
    if (t < FF) xpart[blockIdx.x * FF + t] = xls[t];
}

// kP: pure A bit-pack. 1 row/wave, 8 independent float4 loads, fold, one 256 B store.
// grid 4096 x 256 (4 rows/block). No LDS, no syncs, no shuffles -> max waves, max MLP.
__global__ __launch_bounds__(256) void kP_pack(const float* __restrict__ A,
                                               unsigned* __restrict__ pk) {
    const int t = threadIdx.x;
    const int lane = t & 63, wave = t >> 6;
    const int row = blockIdx.x * 4 + wave;
    const float4* Ar = (const float4*)(A + (size_t)row * NN);

    const float4 v0 = Ar[0 * 64 + lane], v1 = Ar[1 * 64 + lane];
    const float4 v2 = Ar[2 * 64 + lane], v3 = Ar[3 * 64 + lane];
    const float4 v4 = Ar[4 * 64 + lane], v5 = Ar[5 * 64 + lane];
    const float4 v6 = Ar[6 * 64 + lane], v7 = Ar[7 * 64 + lane];

    unsigned m = 0u;
#define NIB(v) ((v.x != 0.f ? 1u : 0u) | (v.y != 0.f ? 2u : 0u) | \
                (v.z != 0.f ? 4u : 0u) | (v.w != 0.f ? 8u : 0u))
    m |= NIB(v0) << 0;  m |= NIB(v1) << 4;  m |= NIB(v2) << 8;  m |= NIB(v3) << 12;
    m |= NIB(v4) << 16; m |= NIB(v5) << 20; m |= NIB(v6) << 24; m |= NIB(v7) << 28;
#undef NIB
    pk[(size_t)row * 64 + lane] = m;
}

// kB: block 0: xsum = reduce(xpart, 512 partials); S = xsum . W.
//     blocks 1..2048: r[row] = p[row] / (pk[row,:] . p[b,:]) (0 if denom==0)
__global__ __launch_bounds__(256) void kB_r(const float* __restrict__ W,
                                            const float* __restrict__ xpart,
                                            const float* __restrict__ p,
                                            const unsigned* __restrict__ pk,
                                            float* __restrict__ r,
                                            float* __restrict__ S) {
    __shared__ float p_lds[NN];
    const int t = threadIdx.x;

    if (blockIdx.x == 0) {
#pragma unroll
        for (int k = 0; k < 4; ++k) {
            const int o = t + 256 * k;            // (b,f), o in [0,1024)
            const int b = o >> 7, f = o & 127;
            float s = 0.f;
            for (int j = 0; j < 64; ++j) s += xpart[(b * 64 + j) * FF + f];
            p_lds[o] = s;
        }
        __syncthreads();
#pragma unroll
        for (int k = 0; k < 4; ++k) {
            const int o = t + 256 * k;
            const int b = o >> 7, f = o & 127;
            float s = 0.f;
#pragma unroll 8
            for (int c = 0; c < FF; ++c) s += p_lds[b * FF + c] * W[c * FF + f];
            S[o] = s;
        }
        return;
    }

    const int row0 = (blockIdx.x - 1) * 8;
    const int b = row0 >> 11;
    const float4* p4 = (const float4*)(p + (size_t)b * NN);
    float4* pl4 = (float4*)p_lds;
    pl4[t]       = p4[t];
    pl4[t + 256] = p4[t + 256];
    __syncthreads();

    const int lane = t & 63, wave = t >> 6;
    const int rowA = row0 + wave * 2;
    const int rowB = rowA + 1;
    const unsigned wA = pk[(size_t)rowA * 64 + lane];
    const unsigned wB = pk[(size_t)rowB * 64 + lane];

    float accA = 0.f, accB = 0.f;
#pragma unroll
    for (int it = 0; it < 8; ++it) {
        const float4 pv = pl4[it * 64 + lane];
        const unsigned na = (wA >> (it * 4)) & 15u;
        const unsigned nb = (wB >> (it * 4)) & 15u;
        accA += (na & 1u) ? pv.x : 0.f;  accB += (nb & 1u) ? pv.x : 0.f;
        accA += (na & 2u) ? pv.y : 0.f;  accB += (nb & 2u) ? pv.y : 0.f;
        accA += (na & 4u) ? pv.z : 0.f;  accB += (nb & 4u) ? pv.z : 0.f;
        accA += (na & 8u) ? pv.w : 0.f;  accB += (nb & 8u) ? pv.w : 0.f;
    }
#pragma unroll
    for (int off = 32; off; off >>= 1) {
        accA += __shfl_xor(accA, off, 64);
        accB += __shfl_xor(accB, off, 64);
    }
    if (lane == 0) {
        const int lr = rowA & (NN - 1);
        r[rowA] = (accA != 0.f) ? (p_lds[lr] / accA) : 0.f;
        r[rowB] = (accB != 0.f) ? (p_lds[lr + 1] / accB) : 0.f;
    }
}

// kC: H[row,f] = (pk[row,:] . r[b,:]) * S[b,f] + bias_W[f]
__global__ __launch_bounds__(256) void kC_H(const unsigned* __restrict__ pk,
                                            const float* __restrict__ rr,
                                            const float* __restrict__ S,
                                            const float* __restrict__ bias_W,
                                            float* __restrict__ Hout) {
    __shared__ float r_lds[NN];
    __shared__ float sls[FF], bwls[FF];
    const int t = threadIdx.x;
    const int row0 = blockIdx.x * 8;
    const int b = row0 >> 11;

    const float4* r4 = (const float4*)(rr + (size_t)b * NN);
    float4* rl4 = (float4*)r_lds;
    rl4[t]       = r4[t];
    rl4[t + 256] = r4[t + 256];
    if (t < FF) { sls[t] = S[b * FF + t]; bwls[t] = bias_W[t]; }
    __syncthreads();

    const int lane = t & 63, wave = t >> 6;
    const int rowA = row0 + wave * 2;
    const int rowB = rowA + 1;
    const unsigned wA = pk[(size_t)rowA * 64 + lane];
    const unsigned wB = pk[(size_t)rowB * 64 + lane];

    float accA = 0.f, accB = 0.f;
#pragma unroll
    for (int it = 0; it < 8; ++it) {
        const float4 rv = rl4[it * 64 + lane];
        const unsigned na = (wA >> (it * 4)) & 15u;
        const unsigned nb = (wB >> (it * 4)) & 15u;
        accA += (na & 1u) ? rv.x : 0.f;  accB += (nb & 1u) ? rv.x : 0.f;
        accA += (na & 2u) ? rv.y : 0.f;  accB += (nb & 2u) ? rv.y : 0.f;
        accA += (na & 4u) ? rv.z : 0.f;  accB += (nb & 4u) ? rv.z : 0.f;
        accA += (na & 8u) ? rv.w : 0.f;  accB += (nb & 8u) ? rv.w : 0.f;
    }
#pragma unroll
    for (int off = 32; off; off >>= 1) {
        accA += __shfl_xor(accA, off, 64);
        accB += __shfl_xor(accB, off, 64);
    }

    const float2 sv = ((const float2*)sls)[lane];
    const float2 bv = ((const float2*)bwls)[lane];
    float2* H2 = (float2*)Hout;
    H2[(size_t)rowA * 64 + lane] = make_float2(accA * sv.x + bv.x, accA * sv.y + bv.y);
    H2[(size_t)rowB * 64 + lane] = make_float2(accB * sv.x + bv.x, accB * sv.y + bv.y);
}

extern "C" void kernel_launch(void* const* d_in, const int* in_sizes, int n_in,
                              void* d_out, int out_size, void* d_ws, size_t ws_size,
                              hipStream_t stream) {
    const float* X      = (const float*)d_in[0];
    const float* A      = (const float*)d_in[1];
    const float* W      = (const float*)d_in[2];
    const float* a      = (const float*)d_in[3];
    // d_in[4] = bias_a : algebraically cancels (rank-1 den), unused
    const float* bias_W = (const float*)d_in[5];
    float* out = (float*)d_out;

    float* ws    = (float*)d_ws;
    float* xpart = ws;            // 512*128 = 65536
    float* S     = ws + 65536;    // 1024
    float* p     = ws + 66560;    // 16384
    float* r     = ws + 82944;    // 16384
    unsigned* pk = (unsigned*)(ws + 99328);  // u32[B*N*64] = 4 MB

    kX_p_xsum<<<(BB * NN) / 32, 256, 0, stream>>>(X, W, a, p, xpart);
    kP_pack<<<(BB * NN) / 4, 256, 0, stream>>>(A, pk);
    kB_r<<<(BB * NN) / 8 + 1, 256, 0, stream>>>(W, xpart, p, pk, r, S);
    kC_H<<<(BB * NN) / 8, 256, 0, stream>>>(pk, r, S, bias_W, out);
}

// Round 12
// 226.632 us; speedup vs baseline: 1.0635x; 1.0455x over previous
//
#include <hip/hip_runtime.h>

#define BB 8
#define NN 2048
#define FF 128

// ws float layout:
//   [0, 65536)      xpart (512 blocks x 128 col-sums of X)
//   [65536, 66560)  S (BB*FF)
//   [66560, 82944)  p (BB*NN)
//   [82944, 99328)  r (BB*NN)
//   [99328, ...)    pk: u32[B*N*64] in-lane masks (4 MB)
//                   bit (it*4+j) of pk[row*64+lane] = (A[row][it*256+lane*4+j] != 0)

// K1: p[b,n] = exp(X[b,n,:] . w_ai); xpart[blk,:] = column sums of X slice.
// grid 512 x 256; 32 rows/block; half-wave per row; w_ai recomputed per block (W is L2-hot).
__global__ __launch_bounds__(256) void k1_p_xsum(const float* __restrict__ X,
                                                 const float* __restrict__ W,
                                                 const float* __restrict__ av,
                                                 float* __restrict__ p,
                                                 float* __restrict__ xpart) {
    __shared__ float wls[FF];
    __shared__ float xls[FF];
    const int t = threadIdx.x;
    if (t < FF) {
        const float4* W4 = (const float4*)(W + t * FF);
        const float4* a4 = (const float4*)(av + FF);
        float s = 0.f;
#pragma unroll
        for (int f = 0; f < FF / 4; ++f) {
            const float4 w4 = W4[f], aa = a4[f];
            s += w4.x * aa.x + w4.y * aa.y + w4.z * aa.z + w4.w * aa.w;
        }
        wls[t] = s;
        xls[t] = 0.f;
    }
    __syncthreads();

    const int gr0 = blockIdx.x * 32;
    const int lane = t & 63, wave = t >> 6;
    const int half = lane >> 5, l32 = lane & 31;
    const float4 wv = ((const float4*)wls)[l32];
    float4 cs = make_float4(0.f, 0.f, 0.f, 0.f);
    const float4* X4 = (const float4*)(X + (size_t)gr0 * FF);

#pragma unroll
    for (int it = 0; it < 4; ++it) {
        const int rloc = wave * 8 + it * 2 + half;
        const float4 xv = X4[(size_t)rloc * 32 + l32];
        cs.x += xv.x; cs.y += xv.y; cs.z += xv.z; cs.w += xv.w;
        float s = xv.x * wv.x + xv.y * wv.y + xv.z * wv.z + xv.w * wv.w;
#pragma unroll
        for (int off = 16; off; off >>= 1) s += __shfl_xor(s, off, 64);
        if (l32 == 0) p[gr0 + rloc] = expf(s);
    }

    atomicAdd(&xls[l32 * 4 + 0], cs.x);
    atomicAdd(&xls[l32 * 4 + 1], cs.y);
    atomicAdd(&xls[l32 * 4 + 2], cs.z);
    atomicAdd(&xls[l32 * 4 + 3], cs.w);
    __syncthreads();
    if (t < FF) xpart[blockIdx.x * FF + t] = xls[t];
}

// K3: block 0: xsum = reduce(xpart); S = xsum . W.
//     blocks 1..2048: r[b,i] = p[b,i] / (A[b,i,:] . p[b,:]) (0 if denom==0)
//     + in-lane bit-pack of A into pk. 2 rows/wave; 16-load straight-line batch.
__global__ __launch_bounds__(256) void k3_r(const float* __restrict__ A,
                                            const float* __restrict__ W,
                                            const float* __restrict__ xpart,
                                            const float* __restrict__ p,
                                            float* __restrict__ r,
                                            float* __restrict__ S,
                                            unsigned* __restrict__ pk) {
    __shared__ float p_lds[NN];
    const int t = threadIdx.x;

    if (blockIdx.x == 0) {
#pragma unroll
        for (int k = 0; k < 4; ++k) {
            const int o = t + 256 * k;            // (b,f), o in [0,1024)
            const int b = o >> 7, f = o & 127;
            float s = 0.f;
            for (int j = 0; j < 64; ++j) s += xpart[(b * 64 + j) * FF + f];
            p_lds[o] = s;
        }
        __syncthreads();
#pragma unroll
        for (int k = 0; k < 4; ++k) {
            const int o = t + 256 * k;
            const int b = o >> 7, f = o & 127;
            float s = 0.f;
#pragma unroll 8
            for (int c = 0; c < FF; ++c) s += p_lds[b * FF + c] * W[c * FF + f];
            S[o] = s;
        }
        return;
    }

    const int row0 = (blockIdx.x - 1) * 8;
    const int b = row0 >> 11;
    const float4* p4 = (const float4*)(p + (size_t)b * NN);
    float4* pl4 = (float4*)p_lds;
    pl4[t]       = p4[t];
    pl4[t + 256] = p4[t + 256];
    __syncthreads();

    const int lane = t & 63, wave = t >> 6;
    const int rowA = row0 + wave * 2;
    const int rowB = rowA + 1;
    const float4* Aa = (const float4*)(A + (size_t)rowA * NN);
    const float4* Ab = (const float4*)(A + (size_t)rowB * NN);

    // straight-line 16-load batch: all A traffic in flight before any fold
    const float4 va0 = Aa[0 * 64 + lane], va1 = Aa[1 * 64 + lane];
    const float4 va2 = Aa[2 * 64 + lane], va3 = Aa[3 * 64 + lane];
    const float4 va4 = Aa[4 * 64 + lane], va5 = Aa[5 * 64 + lane];
    const float4 va6 = Aa[6 * 64 + lane], va7 = Aa[7 * 64 + lane];
    const float4 vb0 = Ab[0 * 64 + lane], vb1 = Ab[1 * 64 + lane];
    const float4 vb2 = Ab[2 * 64 + lane], vb3 = Ab[3 * 64 + lane];
    const float4 vb4 = Ab[4 * 64 + lane], vb5 = Ab[5 * 64 + lane];
    const float4 vb6 = Ab[6 * 64 + lane], vb7 = Ab[7 * 64 + lane];
    __builtin_amdgcn_sched_barrier(0);

    float accA = 0.f, accB = 0.f;
    unsigned mA = 0u, mB = 0u;
#define STEP(K, VA, VB) {                                                     \
        const float4 pv = pl4[K * 64 + lane];                                 \
        accA += VA.x * pv.x + VA.y * pv.y + VA.z * pv.z + VA.w * pv.w;        \
        accB += VB.x * pv.x + VB.y * pv.y + VB.z * pv.z + VB.w * pv.w;        \
        const unsigned na = (VA.x != 0.f ? 1u : 0u) | (VA.y != 0.f ? 2u : 0u) \
                          | (VA.z != 0.f ? 4u : 0u) | (VA.w != 0.f ? 8u : 0u);\
        const unsigned nb = (VB.x != 0.f ? 1u : 0u) | (VB.y != 0.f ? 2u : 0u) \
                          | (VB.z != 0.f ? 4u : 0u) | (VB.w != 0.f ? 8u : 0u);\
        mA |= na << (K * 4); mB |= nb << (K * 4); }
    STEP(0, va0, vb0) STEP(1, va1, vb1) STEP(2, va2, vb2) STEP(3, va3, vb3)
    STEP(4, va4, vb4) STEP(5, va5, vb5) STEP(6, va6, vb6) STEP(7, va7, vb7)
#undef STEP

    pk[(size_t)rowA * 64 + lane] = mA;
    pk[(size_t)rowB * 64 + lane] = mB;

#pragma unroll
    for (int off = 32; off; off >>= 1) {
        accA += __shfl_xor(accA, off, 64);
        accB += __shfl_xor(accB, off, 64);
    }
    if (lane == 0) {
        const int lr = rowA & (NN - 1);
        r[rowA] = (accA != 0.f) ? (p_lds[lr] / accA) : 0.f;
        r[rowB] = (accB != 0.f) ? (p_lds[lr + 1] / accB) : 0.f;
    }
}

// K4: H[b,i,f] = (A[b,i,:] . r[b,:]) * S[b,f] + bias_W[f]
// Reads in-lane masks (4 MB, cache-resident); no shuffles in the inner loop.
__global__ __launch_bounds__(256) void k4_H(const unsigned* __restrict__ pk,
                                            const float* __restrict__ rr,
                                            const float* __restrict__ S,
                                            const float* __restrict__ bias_W,
                                            float* __restrict__ Hout) {
    __shared__ float r_lds[NN];
    __shared__ float sls[FF], bwls[FF];
    const int t = threadIdx.x;
    const int row0 = blockIdx.x * 8;
    const int b = row0 >> 11;

    const float4* r4 = (const float4*)(rr + (size_t)b * NN);
    float4* rl4 = (float4*)r_lds;
    rl4[t]       = r4[t];
    rl4[t + 256] = r4[t + 256];
    if (t < FF) { sls[t] = S[b * FF + t]; bwls[t] = bias_W[t]; }
    __syncthreads();

    const int lane = t & 63, wave = t >> 6;
    const int rowA = row0 + wave * 2;
    const int rowB = rowA + 1;
    const unsigned wA = pk[(size_t)rowA * 64 + lane];
    const unsigned wB = pk[(size_t)rowB * 64 + lane];

    float accA = 0.f, accB = 0.f;
#pragma unroll
    for (int it = 0; it < 8; ++it) {
        const float4 rv = rl4[it * 64 + lane];
        const unsigned na = (wA >> (it * 4)) & 15u;
        const unsigned nb = (wB >> (it * 4)) & 15u;
        accA += (na & 1u) ? rv.x : 0.f;  accB += (nb & 1u) ? rv.x : 0.f;
        accA += (na & 2u) ? rv.y : 0.f;  accB += (nb & 2u) ? rv.y : 0.f;
        accA += (na & 4u) ? rv.z : 0.f;  accB += (nb & 4u) ? rv.z : 0.f;
        accA += (na & 8u) ? rv.w : 0.f;  accB += (nb & 8u) ? rv.w : 0.f;
    }
#pragma unroll
    for (int off = 32; off; off >>= 1) {
        accA += __shfl_xor(accA, off, 64);
        accB += __shfl_xor(accB, off, 64);
    }

    const float2 sv = ((const float2*)sls)[lane];
    const float2 bv = ((const float2*)bwls)[lane];
    float2* H2 = (float2*)Hout;
    H2[(size_t)rowA * 64 + lane] = make_float2(accA * sv.x + bv.x, accA * sv.y + bv.y);
    H2[(size_t)rowB * 64 + lane] = make_float2(accB * sv.x + bv.x, accB * sv.y + bv.y);
}

extern "C" void kernel_launch(void* const* d_in, const int* in_sizes, int n_in,
                              void* d_out, int out_size, void* d_ws, size_t ws_size,
                              hipStream_t stream) {
    const float* X      = (const float*)d_in[0];
    const float* A      = (const float*)d_in[1];
    const float* W      = (const float*)d_in[2];
    const float* a      = (const float*)d_in[3];
    // d_in[4] = bias_a : algebraically cancels (rank-1 den), unused
    const float* bias_W = (const float*)d_in[5];
    float* out = (float*)d_out;

    float* ws    = (float*)d_ws;
    float* xpart = ws;            // 65536
    float* S     = ws + 65536;    // 1024
    float* p     = ws + 66560;    // 16384
    float* r     = ws + 82944;    // 16384
    unsigned* pk = (unsigned*)(ws + 99328);  // u32[B*N*64] = 4 MB

    k1_p_xsum<<<(BB * NN) / 32, 256, 0, stream>>>(X, W, a, p, xpart);
    k3_r<<<(BB * NN) / 8 + 1, 256, 0, stream>>>(A, W, xpart, p, r, S, pk);
    k4_H<<<(BB * NN) / 8, 256, 0, stream>>>(pk, r, S, bias_W, out);
}